// Round 3
// baseline (417.183 us; speedup 1.0000x reference)
//
#include <hip/hip_runtime.h>

#define BB 32
#define TT 4096
#define DD 512
#define HH 8
#define HDD 64
#define SCALE_F 0.125f   // 64^-0.5 exact
#define CHUNKS 16        // chunks per batch (256 rows each) -> grid 512 = 2 blocks/CU, one round
#define TC 256           // rows per chunk
#define RW 64            // rows per wave (4 waves per block)

// DPP-based partner-add: x + x[partner(lane)] for partners within 16-lane rows.
// CTRL: 0xB1 = quad_perm(1,0,3,2) -> xor1 ; 0x4E = quad_perm(2,3,0,1) -> xor2 ;
//       0x141 = row_half_mirror ; 0x128 = row_ror:8 -> xor8 within 16-lane row.
template<int CTRL>
__device__ __forceinline__ float dpp_add(float x) {
    int t = __builtin_amdgcn_update_dpp(0, __float_as_int(x), CTRL, 0xf, 0xf, true);
    return x + __int_as_float(t);
}

// Full 64-lane all-reduce of 8 per-head partial dots; every lane ends with all
// 8 head weights exp()'d. (R2-verified numerics.)
__device__ __forceinline__ void row_weights(const float4* uA, const float4* uB,
                                            float4 e0, float4 e1, float* wv) {
    float a[HH];
#pragma unroll
    for (int h = 0; h < HH; ++h)
        a[h] = uA[h].x * e0.x + uA[h].y * e0.y + uA[h].z * e0.z + uA[h].w * e0.w
             + uB[h].x * e1.x + uB[h].y * e1.y + uB[h].z * e1.z + uB[h].w * e1.w;
#pragma unroll
    for (int h = 0; h < HH; ++h) {
        a[h] = dpp_add<0xB1>(a[h]);    // xor1
        a[h] = dpp_add<0x4E>(a[h]);    // xor2
        a[h] = dpp_add<0x141>(a[h]);   // half-mirror (quads uniform)
        a[h] = dpp_add<0x128>(a[h]);   // row_ror:8 -> xor8
    }
#pragma unroll
    for (int h = 0; h < HH; ++h) a[h] += __shfl_xor(a[h], 16, 64);
#pragma unroll
    for (int h = 0; h < HH; ++h) a[h] += __shfl_xor(a[h], 32, 64);
#pragma unroll
    for (int h = 0; h < HH; ++h) wv[h] = __expf(a[h]);
}

// ---------------- A: u[b,h,:] = SCALE * Wk_h^T (Wq_h . enc[b,-1,:]) ----------
__global__ __launch_bounds__(256) void k_qu(const float* __restrict__ enc,
                                            const float* __restrict__ Wq,
                                            const float* __restrict__ Wk,
                                            float* __restrict__ u) {
    __shared__ float x[DD];
    __shared__ float qh[HDD];
    int b = blockIdx.x >> 3, h = blockIdx.x & 7;
    int tid = threadIdx.x;
    const float* el = enc + ((size_t)b * TT + (TT - 1)) * DD;
    for (int i = tid; i < DD; i += 256) x[i] = el[i];
    __syncthreads();
    if (tid < HDD) {
        const float4* wr = (const float4*)(Wq + (size_t)(h * HDD + tid) * DD);
        float acc = 0.f;
#pragma unroll 4
        for (int d = 0; d < DD / 4; ++d) {
            float4 w = wr[d];
            acc += w.x * x[4 * d] + w.y * x[4 * d + 1] + w.z * x[4 * d + 2] + w.w * x[4 * d + 3];
        }
        qh[tid] = acc;
    }
    __syncthreads();
#pragma unroll
    for (int k = 0; k < 2; ++k) {
        int d = tid + 256 * k;
        float acc = 0.f;
#pragma unroll 8
        for (int j = 0; j < HDD; ++j)
            acc += qh[j] * Wk[(size_t)(h * HDD + j) * DD + d];
        u[(size_t)(b * HH + h) * DD + d] = acc * SCALE_F;
    }
}

// ---------------- B: wave-autonomous fused scores+exp+wsum ------------------
// Row-PAIR main loop: 4 rows resident in registers (2 current + 2 in flight),
// two independent reduce chains per iteration for latency overlap.
__global__ __launch_bounds__(256) void k_main(const float* __restrict__ enc,
                                              const float* __restrict__ u,
                                              float* __restrict__ wt,
                                              float* __restrict__ lsum,
                                              float* __restrict__ partial) {
    __shared__ float red[4][HH][DD];   // 64 KiB
    __shared__ float ls[HH];
    int b = blockIdx.x / CHUNKS, c = blockIdx.x % CHUNKS;
    int t0 = c * TC;
    int tid = threadIdx.x, wave = tid >> 6, lane = tid & 63;
    if (tid < HH) ls[tid] = 0.f;
    __syncthreads();

    const float* ub = u + (size_t)b * HH * DD;
    float4 uA[HH], uB[HH];
#pragma unroll
    for (int h = 0; h < HH; ++h) {
        uA[h] = *(const float4*)(ub + h * DD + 4 * lane);
        uB[h] = *(const float4*)(ub + h * DD + 256 + 4 * lane);
    }

    float4 accA[HH], accB[HH];
#pragma unroll
    for (int h = 0; h < HH; ++h) {
        accA[h] = make_float4(0.f, 0.f, 0.f, 0.f);
        accB[h] = make_float4(0.f, 0.f, 0.f, 0.f);
    }
    float Lacc[HH];
#pragma unroll
    for (int h = 0; h < HH; ++h) Lacc[h] = 0.f;

    int trow = t0 + wave * RW;
    const float* rp = enc + ((size_t)b * TT + trow) * DD;
    float* wp = wt + ((size_t)(b * HH + (lane & 7)) * TT) + trow;
    bool st = lane < HH;
    bool m1 = (lane & 1) != 0, m2 = (lane & 2) != 0, m4 = (lane & 4) != 0;

    // 4 rows resident: p = rows i,i+1 (current), q = rows i+2,i+3 (in flight)
    float4 p0a = *(const float4*)(rp + 4 * lane);
    float4 p0b = *(const float4*)(rp + 256 + 4 * lane);
    float4 p1a = *(const float4*)(rp + DD + 4 * lane);
    float4 p1b = *(const float4*)(rp + DD + 256 + 4 * lane);
    float4 q0a = *(const float4*)(rp + 2 * DD + 4 * lane);
    float4 q0b = *(const float4*)(rp + 2 * DD + 256 + 4 * lane);
    float4 q1a = *(const float4*)(rp + 3 * DD + 4 * lane);
    float4 q1b = *(const float4*)(rp + 3 * DD + 256 + 4 * lane);

    for (int i = 0; i < RW; i += 2) {
        // issue next pair's loads (wrap-masked index keeps it branchless; the
        // two wrapped re-loads at the tail are L2-warm and harmless)
        int r4 = (i + 4) & (RW - 1), r5 = (i + 5) & (RW - 1);
        const float* np4 = rp + (size_t)r4 * DD;
        const float* np5 = rp + (size_t)r5 * DD;
        float4 n0a = *(const float4*)(np4 + 4 * lane);
        float4 n0b = *(const float4*)(np4 + 256 + 4 * lane);
        float4 n1a = *(const float4*)(np5 + 4 * lane);
        float4 n1b = *(const float4*)(np5 + 256 + 4 * lane);

        // two independent reduce chains
        float wv0[HH], wv1[HH];
        row_weights(uA, uB, p0a, p0b, wv0);
        row_weights(uA, uB, p1a, p1b, wv1);

#pragma unroll
        for (int h = 0; h < HH; ++h) { Lacc[h] += wv0[h] + wv1[h]; }

        // wt store: lane h stores head h (binary cndmask select), both rows
        {
            float s01 = m1 ? wv0[1] : wv0[0], s23 = m1 ? wv0[3] : wv0[2];
            float s45 = m1 ? wv0[5] : wv0[4], s67 = m1 ? wv0[7] : wv0[6];
            float sA = m2 ? s23 : s01, sB = m2 ? s67 : s45;
            float ws0 = m4 ? sB : sA;
            float t01 = m1 ? wv1[1] : wv1[0], t23 = m1 ? wv1[3] : wv1[2];
            float t45 = m1 ? wv1[5] : wv1[4], t67 = m1 ? wv1[7] : wv1[6];
            float tA = m2 ? t23 : t01, tB = m2 ? t67 : t45;
            float ws1 = m4 ? tB : tA;
            if (st) { wp[i] = ws0; wp[i + 1] = ws1; }
        }

        // weighted-sum accumulate, both rows
#pragma unroll
        for (int h = 0; h < HH; ++h) {
            accA[h].x += wv0[h] * p0a.x + wv1[h] * p1a.x;
            accA[h].y += wv0[h] * p0a.y + wv1[h] * p1a.y;
            accA[h].z += wv0[h] * p0a.z + wv1[h] * p1a.z;
            accA[h].w += wv0[h] * p0a.w + wv1[h] * p1a.w;
            accB[h].x += wv0[h] * p0b.x + wv1[h] * p1b.x;
            accB[h].y += wv0[h] * p0b.y + wv1[h] * p1b.y;
            accB[h].z += wv0[h] * p0b.z + wv1[h] * p1b.z;
            accB[h].w += wv0[h] * p0b.w + wv1[h] * p1b.w;
        }

        // rotate the ring
        p0a = q0a; p0b = q0b; p1a = q1a; p1b = q1b;
        q0a = n0a; q0b = n0b; q1a = n1a; q1b = n1b;
    }

    // ---- cross-wave reduction via LDS (one barrier per chunk) ----
#pragma unroll
    for (int h = 0; h < HH; ++h) {
        *(float4*)&red[wave][h][4 * lane] = accA[h];
        *(float4*)&red[wave][h][256 + 4 * lane] = accB[h];
    }
    if (lane == 0) {
#pragma unroll
        for (int h = 0; h < HH; ++h) atomicAdd(&ls[h], Lacc[h]);
    }
    __syncthreads();
    {
        int h = tid >> 5, col = (tid & 31) * 4;
        float* pb = partial + ((size_t)(b * CHUNKS + c) * HH + h) * DD;
#pragma unroll
        for (int j = 0; j < 4; ++j) {
            float4 r0 = *(const float4*)&red[0][h][col + 128 * j];
            float4 r1 = *(const float4*)&red[1][h][col + 128 * j];
            float4 r2 = *(const float4*)&red[2][h][col + 128 * j];
            float4 r3 = *(const float4*)&red[3][h][col + 128 * j];
            float4 o = make_float4(r0.x + r1.x + r2.x + r3.x,
                                   r0.y + r1.y + r2.y + r3.y,
                                   r0.z + r1.z + r2.z + r3.z,
                                   r0.w + r1.w + r2.w + r3.w);
            *(float4*)(pb + col + 128 * j) = o;
        }
    }
    if (tid < HH) lsum[(size_t)(b * CHUNKS + c) * HH + tid] = ls[tid];
}

// ---------------- C: ctx reduce + normalize + Wv dot  (grid B*H) -------------
__global__ __launch_bounds__(256) void k_vctx(const float* __restrict__ partial,
                                              const float* __restrict__ lsum,
                                              const float* __restrict__ Wv,
                                              float* __restrict__ ctxv) {
    __shared__ float cs[DD];
    __shared__ float Linv;
    int b = blockIdx.x >> 3, h = blockIdx.x & 7;
    int tid = threadIdx.x;
    if (tid == 0) {
        float L = 0.f;
#pragma unroll 8
        for (int c = 0; c < CHUNKS; ++c) L += lsum[(size_t)(b * CHUNKS + c) * HH + h];
        Linv = 1.0f / L;
    }
    float a0 = 0.f, a1 = 0.f;
    const float* pb = partial + (size_t)(b * CHUNKS) * HH * DD + (size_t)h * DD;
#pragma unroll 8
    for (int c = 0; c < CHUNKS; ++c) {
        const float* pp = pb + (size_t)c * HH * DD;
        a0 += pp[tid]; a1 += pp[tid + 256];
    }
    __syncthreads();
    cs[tid] = a0 * Linv; cs[tid + 256] = a1 * Linv;
    __syncthreads();
    int out = tid >> 2, q = tid & 3;
    int i = h * HDD + out;
    const float4* wr = (const float4*)(Wv + (size_t)i * DD + q * 128);
    const float* cc = cs + q * 128;
    float acc = 0.f;
#pragma unroll 8
    for (int d = 0; d < 32; ++d) {
        float4 w = wr[d];
        acc += w.x * cc[4 * d] + w.y * cc[4 * d + 1] + w.z * cc[4 * d + 2] + w.w * cc[4 * d + 3];
    }
    acc += __shfl_xor(acc, 1, 64);
    acc += __shfl_xor(acc, 2, 64);
    if (q == 0) ctxv[(size_t)b * DD + i] = acc;
}

// ---------------- fused tail: out0 (Wo dot) + out1 (weights mean) ------------
// blocks [0, B*H)       : out0[b, g*64+o] = Wo[g*64+o,:] . ctxv[b,:]
// blocks [B*H, 2*B*H)   : out1[b, seg*512 + t] = (1/8) sum_h wt[b,h,t]/L[b,h]
__global__ __launch_bounds__(256) void k_tail(const float* __restrict__ ctxv,
                                              const float* __restrict__ Wo,
                                              const float* __restrict__ wt,
                                              const float* __restrict__ lsum,
                                              float* __restrict__ out0,
                                              float* __restrict__ out1) {
    __shared__ float cs[DD];
    int idx = blockIdx.x;
    int tid = threadIdx.x;
    if (idx < BB * HH) {
        int b = idx >> 3, g = idx & 7;
        for (int i = tid; i < DD; i += 256) cs[i] = ctxv[(size_t)b * DD + i];
        __syncthreads();
        int out = tid >> 2, q = tid & 3;
        int o = g * HDD + out;
        const float4* wr = (const float4*)(Wo + (size_t)o * DD + q * 128);
        const float* cc = cs + q * 128;
        float acc = 0.f;
#pragma unroll 8
        for (int d = 0; d < 32; ++d) {
            float4 w = wr[d];
            acc += w.x * cc[4 * d] + w.y * cc[4 * d + 1] + w.z * cc[4 * d + 2] + w.w * cc[4 * d + 3];
        }
        acc += __shfl_xor(acc, 1, 64);
        acc += __shfl_xor(acc, 2, 64);
        if (q == 0) out0[(size_t)b * DD + o] = acc;
    } else {
        idx -= BB * HH;
        int b = idx >> 3, seg = idx & 7;
        if (tid < HH) {
            float s = 0.f;
#pragma unroll 8
            for (int c = 0; c < CHUNKS; ++c) s += lsum[(size_t)(b * CHUNKS + c) * HH + tid];
            cs[tid] = 0.125f / s;
        }
        __syncthreads();
#pragma unroll
        for (int k = 0; k < 2; ++k) {
            int t = seg * 512 + tid + 256 * k;
            float s = 0.f;
#pragma unroll
            for (int h = 0; h < HH; ++h)
                s += wt[(size_t)(b * HH + h) * TT + t] * cs[h];
            out1[(size_t)b * TT + t] = s;
        }
    }
}

extern "C" void kernel_launch(void* const* d_in, const int* in_sizes, int n_in,
                              void* d_out, int out_size, void* d_ws, size_t ws_size,
                              hipStream_t stream) {
    const float* enc = (const float*)d_in[0];
    const float* Wq  = (const float*)d_in[1];
    const float* Wk  = (const float*)d_in[2];
    const float* Wv  = (const float*)d_in[3];
    const float* Wo  = (const float*)d_in[4];

    float* ws = (float*)d_ws;
    float* u       = ws;                                      // B*H*D        = 131072
    float* wt      = u + (size_t)BB * HH * DD;                // B*H*T        = 1048576
    float* lsum    = wt + (size_t)BB * HH * TT;               // B*CHUNKS*H   = 4096
    float* partial = lsum + (size_t)BB * CHUNKS * HH;         // B*CHUNKS*H*D = 2097152
    float* ctxv    = partial + (size_t)BB * CHUNKS * HH * DD; // B*D          = 16384

    float* out0 = (float*)d_out;          // [B, D]
    float* out1 = out0 + BB * DD;         // [B, T]

    hipLaunchKernelGGL(k_qu,    dim3(BB * HH),     dim3(256), 0, stream, enc, Wq, Wk, u);
    hipLaunchKernelGGL(k_main,  dim3(BB * CHUNKS), dim3(256), 0, stream, enc, u, wt, lsum, partial);
    hipLaunchKernelGGL(k_vctx,  dim3(BB * HH),     dim3(256), 0, stream, partial, lsum, Wv, ctxv);
    hipLaunchKernelGGL(k_tail,  dim3(2 * BB * HH), dim3(256), 0, stream, ctxv, Wo, wt, lsum, out0, out1);
}